// Round 5
// baseline (288.267 us; speedup 1.0000x reference)
//
#include <hip/hip_runtime.h>
#include <hip/hip_fp16.h>
#include <cstdint>

#define T_DIM 64
#define IN_DIM 4100
#define OUT_DIM 12288
#define G_DIM 820
#define KCODE 256
#define GRP 5
#define KB16 410         /* k-blocks of 16 (2 padded groups each) */
#define CHUNKS 41        /* 20 groups per chunk = 10 k16-steps */
#define CH_G 20
#define KSPLIT 4
#define NBLK 192         /* 12288 / 64 */
#define LDS_STRIDE 168   /* halfs; 336 B/row -> phase-20 bank walk, conflict-free */

typedef _Float16 f16x8 __attribute__((ext_vector_type(8)));
typedef float f32x4 __attribute__((ext_vector_type(4)));
typedef float f32x16 __attribute__((ext_vector_type(16)));

__device__ float g_pmax[256];                            // per-block |x| partial max
__device__ float g_cbmax;                                // clamped cb_max
__device__ float g_xmax;                                 // clamped x_max*8
__device__ int   g_cnt[NBLK];                            // K-split arrival counters
__device__ __align__(16) _Float16 g_cbq[2 * KCODE * 8];  // padded, pre-scaled fp16 cb
__device__ __align__(16) _Float16 g_xA[2 * KB16 * 64 * 8]; // A-frags, 32x32x16 lane order
__device__ __align__(16) float g_part[KSPLIT * T_DIM * OUT_DIM];

__device__ __forceinline__ float block_reduce_max(float m, float* sm) {
    for (int off = 32; off > 0; off >>= 1)
        m = fmaxf(m, __shfl_down(m, off));
    int tid = threadIdx.x;
    if ((tid & 63) == 0) sm[tid >> 6] = m;
    __syncthreads();
    float r = fmaxf(fmaxf(sm[0], sm[1]), fmaxf(sm[2], sm[3]));
    __syncthreads();
    return r;
}

// K1: per-block |x| partial max; block 0 canonicalizes + scales cb; zero counters.
__global__ void __launch_bounds__(256) k1_absmax_cb(const float* __restrict__ x,
                                                    const void* __restrict__ cbraw) {
    __shared__ float sm[4];
    int tid = threadIdx.x, bid = blockIdx.x;
    if (tid == 0 && bid < NBLK) g_cnt[bid] = 0;
    float m = 0.f;
    for (int i = bid * 256 + tid; i < T_DIM * IN_DIM; i += 256 * 256)
        m = fmaxf(m, fabsf(x[i]));
    float r = block_reduce_max(m, sm);
    if (tid == 0) g_pmax[bid] = r;

    if (bid == 0) {
        // dtype probe (verified R2): fp16 codebooks may arrive upcast to f32.
        unsigned u0 = *(const unsigned*)cbraw;
        bool is_f32 = (((u0 >> 23) & 0xFF) >= 100);
        float mm = 0.f;
        for (int i = tid; i < 2 * KCODE * GRP; i += 256) {
            float v = is_f32 ? ((const float*)cbraw)[i]
                             : (float)((const _Float16*)cbraw)[i];
            mm = fmaxf(mm, fabsf(v));
        }
        float cbm = fmaxf(block_reduce_max(mm, sm), 1.0f);
        if (tid == 0) g_cbmax = cbm;
        for (int e = tid; e < 2 * KCODE; e += 256) {
            f16x8 v = {};
            #pragma unroll
            for (int j = 0; j < GRP; ++j) {
                float w = is_f32 ? ((const float*)cbraw)[e * GRP + j]
                                 : (float)((const _Float16*)cbraw)[e * GRP + j];
                v[j] = (_Float16)(w / cbm);
            }
            *(f16x8*)&g_cbq[e * 8] = v;
        }
    }
}

// K2: reduce partials -> xm; quantize x into 32x32x16 A-fragment order.
// g_xA[((tt*KB16 + kb)*64 + lane)*8 + j] = fp16(x[tt*32+(lane&31)]
//                                                [(kb*2+(lane>>5))*5 + j] / xm), j<5
__global__ void __launch_bounds__(256) k2_quant(const float* __restrict__ x) {
    __shared__ float sm[4];
    int tid = threadIdx.x;
    float xm = fmaxf(block_reduce_max(g_pmax[tid], sm), 1.0f) * 8.0f;
    if (blockIdx.x == 0 && tid == 0) g_xmax = xm;

    int gt = blockIdx.x * 256 + tid;        // [0, 205*256) == 2*KB16*64
    int lane = gt & 63;
    int rest = gt >> 6;                     // tt*KB16 + kb
    int kb = rest % KB16;
    int tt = rest / KB16;
    int t = tt * 32 + (lane & 31);
    int g = kb * 2 + (lane >> 5);
    const float* xp = x + (size_t)t * IN_DIM + g * GRP;
    float inv = 1.0f / xm;
    f16x8 v = {};
    #pragma unroll
    for (int j = 0; j < GRP; ++j) v[j] = (_Float16)(xp[j] * inv);
    *(f16x8*)&g_xA[(size_t)gt * 8] = v;
}

// K3: GEMM + fused finalize. 768 blocks (192 o-tiles x KSPLIT=4), 4 waves.
// Tile 64(T)x64(O); each wave one 32x32 MFMA tile; W gathered to LDS;
// A-frags direct from global (L2-resident). Last ksp block per o-tile finalizes.
__global__ void __launch_bounds__(256) k3_gemm(const int* __restrict__ indices,
                                               const float* __restrict__ scales,
                                               float* __restrict__ out) {
    __shared__ alignas(16) _Float16 w_lds[64 * LDS_STRIDE];
    __shared__ f16x8 cb_sh[2 * KCODE];
    __shared__ int s_old;

    int tid = threadIdx.x;
    int nb = blockIdx.x % NBLK;
    int ksp = blockIdx.x / NBLK;
    int n_base = nb * 64;

    for (int e = tid; e < 2 * KCODE; e += 256)
        cb_sh[e] = *(const f16x8*)&g_cbq[e * 8];

    // staging slots: 64 o-rows x 20 groups = 5*256
    int sro[5], sgl[5];
    #pragma unroll
    for (int j = 0; j < 5; ++j) {
        int s = tid + j * 256;
        sro[j] = s / 20; sgl[j] = s - sro[j] * 20;
    }

    const int wid = tid >> 6, lane = tid & 63;
    const int trow = wid >> 1, ocol = wid & 1;
    const int l31 = lane & 31, lh = lane >> 5;

    const int c0 = (CHUNKS * ksp) / KSPLIT;
    const int c1 = (CHUNKS * (ksp + 1)) / KSPLIT;

    f32x16 acc = {};
    int2 idxr[5];
    auto pref_idx = [&](int c) {
        int g0 = c * CH_G;
        #pragma unroll
        for (int j = 0; j < 5; ++j)
            idxr[j] = *(const int2*)&indices[(size_t)(n_base + sro[j]) * (G_DIM * 2)
                                             + (size_t)(g0 + sgl[j]) * 2];
    };

    pref_idx(c0);
    __syncthreads();   // cb_sh ready

    for (int c = c0; c < c1; ++c) {
        // issue A-frag loads for this chunk (L2-resident; complete under staging)
        uint4 ar[10];
        #pragma unroll
        for (int s = 0; s < 10; ++s)
            ar[s] = *(const uint4*)&g_xA[(size_t)(((trow * KB16) + c * 10 + s) * 64 + lane) * 8];
        // stage W tile from prefetched indices (gather + fp16 add, matches ref)
        #pragma unroll
        for (int j = 0; j < 5; ++j) {
            f16x8 w = cb_sh[idxr[j].x] + cb_sh[KCODE + idxr[j].y];
            *(f16x8*)&w_lds[sro[j] * LDS_STRIDE + sgl[j] * 8] = w;
        }
        __syncthreads();            // W tile ready
        if (c + 1 < c1) pref_idx(c + 1);   // next indices fly under MFMA phase
        #pragma unroll
        for (int s = 0; s < 10; ++s) {
            f16x8 a = *(f16x8*)&ar[s];
            f16x8 b = *(const f16x8*)&w_lds[(ocol * 32 + l31) * LDS_STRIDE + s * 16 + lh * 8];
            acc = __builtin_amdgcn_mfma_f32_32x32x16_f16(a, b, acc, 0, 0, 0);
        }
        __syncthreads();            // W tile consumed
    }

    // 32x32 C/D: col = lane&31 (o), row = (reg&3) + 8*(reg>>2) + 4*(lane>>5)
    float* pp = g_part + (size_t)ksp * (T_DIM * OUT_DIM);
    int o = n_base + ocol * 32 + l31;
    #pragma unroll
    for (int r = 0; r < 16; ++r) {
        int t = trow * 32 + 4 * lh + (r & 3) + 8 * (r >> 2);
        pp[t * OUT_DIM + o] = acc[r];
    }

    // fused finalize: last-arriving ksp block for this o-tile sums + scales
    __threadfence();
    if (tid == 0) s_old = atomicAdd(&g_cnt[nb], 1);
    __syncthreads();
    if (s_old == KSPLIT - 1) {
        __threadfence();
        float s = g_xmax * g_cbmax;
        const int TO = T_DIM * OUT_DIM;
        for (int e = tid; e < 64 * 16; e += 256) {
            int t = e >> 4;
            int oc = n_base + (e & 15) * 4;
            const float* pb = g_part + (size_t)t * OUT_DIM + oc;
            f32x4 v = *(const f32x4*)pb;
            v += *(const f32x4*)(pb + TO);
            v += *(const f32x4*)(pb + 2 * TO);
            v += *(const f32x4*)(pb + 3 * TO);
            f32x4 sc = *(const f32x4*)&scales[oc];
            f32x4 r;
            #pragma unroll
            for (int j = 0; j < 4; ++j) {
                float u = v[j] * s * sc[j];
                if (!isfinite(u)) u = 0.f;
                r[j] = u;
            }
            *(f32x4*)&out[(size_t)t * OUT_DIM + oc] = r;
        }
    }
}

extern "C" void kernel_launch(void* const* d_in, const int* in_sizes, int n_in,
                              void* d_out, int out_size, void* d_ws, size_t ws_size,
                              hipStream_t stream) {
    const float* x = (const float*)d_in[0];
    const int* indices = (const int*)d_in[1];
    const void* cbraw = (const void*)d_in[2];
    const float* scales = (const float*)d_in[3];
    float* out = (float*)d_out;
    (void)d_ws; (void)ws_size; (void)n_in; (void)in_sizes; (void)out_size;

    k1_absmax_cb<<<256, 256, 0, stream>>>(x, cbraw);
    k2_quant<<<205, 256, 0, stream>>>(x);
    k3_gemm<<<NBLK * KSPLIT, 256, 0, stream>>>(indices, scales, out);
}

// Round 6
// 268.563 us; speedup vs baseline: 1.0734x; 1.0734x over previous
//
#include <hip/hip_runtime.h>
#include <hip/hip_fp16.h>
#include <cstdint>

#define T_DIM 64
#define IN_DIM 4100
#define OUT_DIM 12288
#define G_DIM 820
#define KCODE 256
#define GRP 5
#define KP 6560          /* padded K' = 820 groups * 8 */
#define KB32 205         /* k-blocks of 32 */
#define CHUNKS 41        /* 20 groups per chunk */
#define CH_G 20
#define KSPLIT 4
#define NBLK 192         /* 12288 / 64 */
#define LDS_STRIDE 168   /* halfs; 336 B/row */

typedef _Float16 f16x8 __attribute__((ext_vector_type(8)));
typedef float f32x4 __attribute__((ext_vector_type(4)));

__device__ float g_pmax[256];                            // per-block |x| partial max
__device__ float g_cbmax;                                // clamped cb_max
__device__ float g_xmax;                                 // clamped x_max*8
__device__ int   g_cnt[NBLK];                            // K-split arrival counters
__device__ __align__(16) _Float16 g_cbq[2 * KCODE * 8];  // padded, pre-scaled fp16 cb
__device__ __align__(16) _Float16 g_xA[4 * KB32 * 64 * 8]; // A-frags, 16x16x32 lane order
__device__ __align__(16) float g_part[KSPLIT * T_DIM * OUT_DIM];

__device__ __forceinline__ float block_reduce_max(float m, float* sm) {
    for (int off = 32; off > 0; off >>= 1)
        m = fmaxf(m, __shfl_down(m, off));
    int tid = threadIdx.x;
    if ((tid & 63) == 0) sm[tid >> 6] = m;
    __syncthreads();
    float r = fmaxf(fmaxf(sm[0], sm[1]), fmaxf(sm[2], sm[3]));
    __syncthreads();
    return r;
}

// K1: per-block |x| partial max; block 0 canonicalizes + scales cb; zero counters.
__global__ void __launch_bounds__(256) k1_absmax_cb(const float* __restrict__ x,
                                                    const void* __restrict__ cbraw) {
    __shared__ float sm[4];
    int tid = threadIdx.x, bid = blockIdx.x;
    if (tid == 0 && bid < NBLK) g_cnt[bid] = 0;
    float m = 0.f;
    for (int i = bid * 256 + tid; i < T_DIM * IN_DIM; i += 256 * 256)
        m = fmaxf(m, fabsf(x[i]));
    float r = block_reduce_max(m, sm);
    if (tid == 0) g_pmax[bid] = r;

    if (bid == 0) {
        // dtype probe (verified R2): fp16 codebooks may arrive upcast to f32.
        unsigned u0 = *(const unsigned*)cbraw;
        bool is_f32 = (((u0 >> 23) & 0xFF) >= 100);
        float mm = 0.f;
        for (int i = tid; i < 2 * KCODE * GRP; i += 256) {
            float v = is_f32 ? ((const float*)cbraw)[i]
                             : (float)((const _Float16*)cbraw)[i];
            mm = fmaxf(mm, fabsf(v));
        }
        float cbm = fmaxf(block_reduce_max(mm, sm), 1.0f);
        if (tid == 0) g_cbmax = cbm;
        for (int e = tid; e < 2 * KCODE; e += 256) {
            f16x8 v = {};
            #pragma unroll
            for (int j = 0; j < GRP; ++j) {
                float w = is_f32 ? ((const float*)cbraw)[e * GRP + j]
                                 : (float)((const _Float16*)cbraw)[e * GRP + j];
                v[j] = (_Float16)(w / cbm);
            }
            *(f16x8*)&g_cbq[e * 8] = v;
        }
    }
}

// K2: reduce partials -> xm; quantize x straight into 16x16x32 A-fragment order.
// g_xA[((t16*KB32 + kb32)*64 + lane)*8 + j] = fp16(x[t16*16+(lane&15)]
//                                                   [(kb32*4+(lane>>4))*5 + j] / xm), j<5
__global__ void __launch_bounds__(256) k2_quant(const float* __restrict__ x) {
    __shared__ float sm[4];
    int tid = threadIdx.x;
    float xm = fmaxf(block_reduce_max(g_pmax[tid], sm), 1.0f) * 8.0f;
    if (blockIdx.x == 0 && tid == 0) g_xmax = xm;

    int gt = blockIdx.x * 256 + tid;        // [0, 205*256) == 4*KB32*64
    int lane = gt & 63;
    int rest = gt >> 6;                     // t16*KB32 + kb32
    int kb32 = rest % KB32;
    int t16 = rest / KB32;
    int r16 = lane & 15, q = lane >> 4;
    int t = t16 * 16 + r16;
    int g = kb32 * 4 + q;
    const float* xp = x + (size_t)t * IN_DIM + g * GRP;
    float inv = 1.0f / xm;
    f16x8 v = {};
    #pragma unroll
    for (int j = 0; j < GRP; ++j) v[j] = (_Float16)(xp[j] * inv);
    *(f16x8*)&g_xA[(size_t)gt * 8] = v;
}

// K3: GEMM (R4-proven structure) + fused finalize via arrival counters.
// 768 blocks (192 o-tiles x KSPLIT=4), 4 waves; tile 64(T)x64(O);
// A-frags direct from global (L2), prefetched one chunk ahead; W gathered to LDS.
__global__ void __launch_bounds__(256) k3_gemm(const int* __restrict__ indices,
                                               const float* __restrict__ scales,
                                               float* __restrict__ out) {
    __shared__ alignas(16) _Float16 w_lds[64 * LDS_STRIDE];
    __shared__ f16x8 cb_sh[2 * KCODE];
    __shared__ int s_old;

    int tid = threadIdx.x;
    int nb = blockIdx.x % NBLK;
    int ksp = blockIdx.x / NBLK;
    int n_base = nb * 64;

    for (int e = tid; e < 2 * KCODE; e += 256)
        cb_sh[e] = *(const f16x8*)&g_cbq[e * 8];

    // per-thread staging slots: 64 o-rows x 20 groups = 5*256
    int sro[5], sgl[5];
    #pragma unroll
    for (int j = 0; j < 5; ++j) {
        int s = tid + j * 256;
        sro[j] = s / 20; sgl[j] = s - sro[j] * 20;
    }

    const int c0 = (CHUNKS * ksp) / KSPLIT;
    const int c1 = (CHUNKS * (ksp + 1)) / KSPLIT;
    const int wid = tid >> 6, lane = tid & 63;
    const int q = lane >> 4, r16 = lane & 15;

    f32x4 acc[4] = {};
    int2 idxr[5];
    uint4 ar[5];
    auto prefetch = [&](int c) {
        int g0 = c * CH_G, kb = c * 5;
        #pragma unroll
        for (int j = 0; j < 5; ++j) {
            ar[j] = *(const uint4*)&g_xA[(size_t)((wid * KB32 + kb + j) * 64 + lane) * 8];
            idxr[j] = *(const int2*)&indices[(size_t)(n_base + sro[j]) * (G_DIM * 2)
                                             + (size_t)(g0 + sgl[j]) * 2];
        }
    };

    prefetch(c0);
    __syncthreads();   // cb_sh ready

    for (int c = c0; c < c1; ++c) {
        // stage W tile from prefetched indices (gather + fp16 add, matches ref)
        #pragma unroll
        for (int j = 0; j < 5; ++j) {
            f16x8 w = cb_sh[idxr[j].x] + cb_sh[KCODE + idxr[j].y];
            *(f16x8*)&w_lds[sro[j] * LDS_STRIDE + sgl[j] * 8] = w;
        }
        uint4 acur[5];
        #pragma unroll
        for (int j = 0; j < 5; ++j) acur[j] = ar[j];
        __syncthreads();            // W tile ready
        if (c + 1 < c1) prefetch(c + 1);   // next A/idx fly under MFMA phase
        #pragma unroll
        for (int kk = 0; kk < 5; ++kk) {
            f16x8 a = *(f16x8*)&acur[kk];
            #pragma unroll
            for (int nt = 0; nt < 4; ++nt) {
                f16x8 b = *(const f16x8*)&w_lds[(nt * 16 + r16) * LDS_STRIDE + kk * 32 + q * 8];
                acc[nt] = __builtin_amdgcn_mfma_f32_16x16x32_f16(a, b, acc[nt], 0, 0, 0);
            }
        }
        __syncthreads();            // W tile consumed
    }

    // C/D: col = lane&15 (o), row = (lane>>4)*4 + reg (t)   [verified R2/R4]
    float* pp = g_part + (size_t)ksp * (T_DIM * OUT_DIM);
    #pragma unroll
    for (int nt = 0; nt < 4; ++nt) {
        #pragma unroll
        for (int rr = 0; rr < 4; ++rr) {
            int t = wid * 16 + q * 4 + rr;
            int o = n_base + nt * 16 + r16;
            pp[t * OUT_DIM + o] = acc[nt][rr];
        }
    }

    // fused finalize: last-arriving ksp block for this o-tile sums + scales
    __threadfence();
    if (tid == 0) s_old = atomicAdd(&g_cnt[nb], 1);
    __syncthreads();
    if (s_old == KSPLIT - 1) {
        __threadfence();
        float s = g_xmax * g_cbmax;
        const int TO = T_DIM * OUT_DIM;
        for (int e = tid; e < 64 * 16; e += 256) {
            int t = e >> 4;
            int oc = n_base + (e & 15) * 4;
            const float* pb = g_part + (size_t)t * OUT_DIM + oc;
            f32x4 v = *(const f32x4*)pb;
            v += *(const f32x4*)(pb + TO);
            v += *(const f32x4*)(pb + 2 * TO);
            v += *(const f32x4*)(pb + 3 * TO);
            f32x4 sc = *(const f32x4*)&scales[oc];
            f32x4 r;
            #pragma unroll
            for (int j = 0; j < 4; ++j) {
                float u = v[j] * s * sc[j];
                if (!isfinite(u)) u = 0.f;
                r[j] = u;
            }
            *(f32x4*)&out[(size_t)t * OUT_DIM + oc] = r;
        }
    }
}

extern "C" void kernel_launch(void* const* d_in, const int* in_sizes, int n_in,
                              void* d_out, int out_size, void* d_ws, size_t ws_size,
                              hipStream_t stream) {
    const float* x = (const float*)d_in[0];
    const int* indices = (const int*)d_in[1];
    const void* cbraw = (const void*)d_in[2];
    const float* scales = (const float*)d_in[3];
    float* out = (float*)d_out;
    (void)d_ws; (void)ws_size; (void)n_in; (void)in_sizes; (void)out_size;

    k1_absmax_cb<<<256, 256, 0, stream>>>(x, cbraw);
    k2_quant<<<205, 256, 0, stream>>>(x);
    k3_gemm<<<NBLK * KSPLIT, 256, 0, stream>>>(indices, scales, out);
}

// Round 7
// 153.514 us; speedup vs baseline: 1.8778x; 1.7494x over previous
//
#include <hip/hip_runtime.h>
#include <hip/hip_fp16.h>
#include <cstdint>

#define T_DIM 64
#define IN_DIM 4100
#define OUT_DIM 12288
#define G_DIM 820
#define KCODE 256
#define GRP 5
#define KP 6560          /* padded K' = 820 groups * 8 */
#define KB32 205         /* k-blocks of 32 */
#define CHUNKS 41        /* 20 groups per chunk */
#define CH_G 20
#define KSPLIT 8
#define NBLK 192         /* 12288 / 64 */
#define LDS_STRIDE 168   /* halfs; 336 B/row */

typedef _Float16 f16x8 __attribute__((ext_vector_type(8)));
typedef float f32x4 __attribute__((ext_vector_type(4)));

__device__ float g_pmax[256];                            // per-block |x| partial max
__device__ float g_cbmax;                                // clamped cb_max
__device__ float g_xmax;                                 // clamped x_max*8
__device__ __align__(16) _Float16 g_cbq[2 * KCODE * 8];  // padded, pre-scaled fp16 cb
__device__ __align__(16) _Float16 g_xA[4 * KB32 * 64 * 8]; // A-frags, 16x16x32 lane order
__device__ __align__(16) float g_part[KSPLIT * T_DIM * OUT_DIM];

__device__ __forceinline__ float block_reduce_max(float m, float* sm) {
    for (int off = 32; off > 0; off >>= 1)
        m = fmaxf(m, __shfl_down(m, off));
    int tid = threadIdx.x;
    if ((tid & 63) == 0) sm[tid >> 6] = m;
    __syncthreads();
    float r = fmaxf(fmaxf(sm[0], sm[1]), fmaxf(sm[2], sm[3]));
    __syncthreads();
    return r;
}

// K1: per-block |x| partial max; block 0 canonicalizes + scales cb.
__global__ void __launch_bounds__(256) k1_absmax_cb(const float* __restrict__ x,
                                                    const void* __restrict__ cbraw) {
    __shared__ float sm[4];
    int tid = threadIdx.x, bid = blockIdx.x;
    float m = 0.f;
    for (int i = bid * 256 + tid; i < T_DIM * IN_DIM; i += 256 * 256)
        m = fmaxf(m, fabsf(x[i]));
    float r = block_reduce_max(m, sm);
    if (tid == 0) g_pmax[bid] = r;

    if (bid == 0) {
        // dtype probe (verified R2): fp16 codebooks may arrive upcast to f32.
        unsigned u0 = *(const unsigned*)cbraw;
        bool is_f32 = (((u0 >> 23) & 0xFF) >= 100);
        float mm = 0.f;
        for (int i = tid; i < 2 * KCODE * GRP; i += 256) {
            float v = is_f32 ? ((const float*)cbraw)[i]
                             : (float)((const _Float16*)cbraw)[i];
            mm = fmaxf(mm, fabsf(v));
        }
        float cbm = fmaxf(block_reduce_max(mm, sm), 1.0f);
        if (tid == 0) g_cbmax = cbm;
        for (int e = tid; e < 2 * KCODE; e += 256) {
            f16x8 v = {};
            #pragma unroll
            for (int j = 0; j < GRP; ++j) {
                float w = is_f32 ? ((const float*)cbraw)[e * GRP + j]
                                 : (float)((const _Float16*)cbraw)[e * GRP + j];
                v[j] = (_Float16)(w / cbm);
            }
            *(f16x8*)&g_cbq[e * 8] = v;
        }
    }
}

// K2: reduce partials -> xm; quantize x straight into 16x16x32 A-fragment order.
__global__ void __launch_bounds__(256) k2_quant(const float* __restrict__ x) {
    __shared__ float sm[4];
    int tid = threadIdx.x;
    float xm = fmaxf(block_reduce_max(g_pmax[tid], sm), 1.0f) * 8.0f;
    if (blockIdx.x == 0 && tid == 0) g_xmax = xm;

    int gt = blockIdx.x * 256 + tid;        // [0, 205*256) == 4*KB32*64
    int lane = gt & 63;
    int rest = gt >> 6;                     // t16*KB32 + kb32
    int kb32 = rest % KB32;
    int t16 = rest / KB32;
    int r16 = lane & 15, q = lane >> 4;
    int t = t16 * 16 + r16;
    int g = kb32 * 4 + q;
    const float* xp = x + (size_t)t * IN_DIM + g * GRP;
    float inv = 1.0f / xm;
    f16x8 v = {};
    #pragma unroll
    for (int j = 0; j < GRP; ++j) v[j] = (_Float16)(xp[j] * inv);
    *(f16x8*)&g_xA[(size_t)gt * 8] = v;
}

// K3: GEMM (R4-proven structure). 1536 blocks (192 o-tiles x KSPLIT=8), 4 waves.
// Tile 64(T)x64(O); A-frags direct from global (L2), prefetched one chunk ahead;
// W gathered to LDS. Pure producer: writes K-split partials only, no fences.
__global__ void __launch_bounds__(256) k3_gemm(const int* __restrict__ indices) {
    __shared__ alignas(16) _Float16 w_lds[64 * LDS_STRIDE];
    __shared__ f16x8 cb_sh[2 * KCODE];

    int tid = threadIdx.x;
    int nb = blockIdx.x % NBLK;
    int ksp = blockIdx.x / NBLK;
    int n_base = nb * 64;

    for (int e = tid; e < 2 * KCODE; e += 256)
        cb_sh[e] = *(const f16x8*)&g_cbq[e * 8];

    // per-thread staging slots: 64 o-rows x 20 groups = 5*256
    int sro[5], sgl[5];
    #pragma unroll
    for (int j = 0; j < 5; ++j) {
        int s = tid + j * 256;
        sro[j] = s / 20; sgl[j] = s - sro[j] * 20;
    }

    const int c0 = (CHUNKS * ksp) / KSPLIT;
    const int c1 = (CHUNKS * (ksp + 1)) / KSPLIT;
    const int wid = tid >> 6, lane = tid & 63;
    const int q = lane >> 4, r16 = lane & 15;

    f32x4 acc[4] = {};
    int2 idxr[5];
    uint4 ar[5];
    auto prefetch = [&](int c) {
        int g0 = c * CH_G, kb = c * 5;
        #pragma unroll
        for (int j = 0; j < 5; ++j) {
            ar[j] = *(const uint4*)&g_xA[(size_t)((wid * KB32 + kb + j) * 64 + lane) * 8];
            idxr[j] = *(const int2*)&indices[(size_t)(n_base + sro[j]) * (G_DIM * 2)
                                             + (size_t)(g0 + sgl[j]) * 2];
        }
    };

    prefetch(c0);
    __syncthreads();   // cb_sh ready

    for (int c = c0; c < c1; ++c) {
        // stage W tile from prefetched indices (gather + fp16 add, matches ref)
        #pragma unroll
        for (int j = 0; j < 5; ++j) {
            f16x8 w = cb_sh[idxr[j].x] + cb_sh[KCODE + idxr[j].y];
            *(f16x8*)&w_lds[sro[j] * LDS_STRIDE + sgl[j] * 8] = w;
        }
        uint4 acur[5];
        #pragma unroll
        for (int j = 0; j < 5; ++j) acur[j] = ar[j];
        __syncthreads();            // W tile ready
        if (c + 1 < c1) prefetch(c + 1);   // next A/idx fly under MFMA phase
        #pragma unroll
        for (int kk = 0; kk < 5; ++kk) {
            f16x8 a = *(f16x8*)&acur[kk];
            #pragma unroll
            for (int nt = 0; nt < 4; ++nt) {
                f16x8 b = *(const f16x8*)&w_lds[(nt * 16 + r16) * LDS_STRIDE + kk * 32 + q * 8];
                acc[nt] = __builtin_amdgcn_mfma_f32_16x16x32_f16(a, b, acc[nt], 0, 0, 0);
            }
        }
        __syncthreads();            // W tile consumed
    }

    // C/D: col = lane&15 (o), row = (lane>>4)*4 + reg (t)   [verified R2/R4]
    float* pp = g_part + (size_t)ksp * (T_DIM * OUT_DIM);
    #pragma unroll
    for (int nt = 0; nt < 4; ++nt) {
        #pragma unroll
        for (int rr = 0; rr < 4; ++rr) {
            int t = wid * 16 + q * 4 + rr;
            int o = n_base + nt * 16 + r16;
            pp[t * OUT_DIM + o] = acc[nt][rr];
        }
    }
}

// K4: sum K-split partials, scale by xm*cbm*scales[o], nan_to_num, store float4.
__global__ void __launch_bounds__(256) k4_final(const float* __restrict__ scales,
                                                float* __restrict__ out) {
    int i4 = blockIdx.x * 256 + threadIdx.x;
    if (i4 >= T_DIM * OUT_DIM / 4) return;
    float s = g_xmax * g_cbmax;
    const f32x4* p = (const f32x4*)g_part;
    const int Q = T_DIM * OUT_DIM / 4;
    f32x4 v = p[i4];
    #pragma unroll
    for (int k = 1; k < KSPLIT; ++k) v += p[k * Q + i4];
    int o4 = i4 % (OUT_DIM / 4);
    f32x4 sc = *(const f32x4*)&scales[o4 * 4];
    f32x4 r;
    #pragma unroll
    for (int j = 0; j < 4; ++j) {
        float u = v[j] * s * sc[j];
        if (!isfinite(u)) u = 0.f;
        r[j] = u;
    }
    ((f32x4*)out)[i4] = r;
}

extern "C" void kernel_launch(void* const* d_in, const int* in_sizes, int n_in,
                              void* d_out, int out_size, void* d_ws, size_t ws_size,
                              hipStream_t stream) {
    const float* x = (const float*)d_in[0];
    const int* indices = (const int*)d_in[1];
    const void* cbraw = (const void*)d_in[2];
    const float* scales = (const float*)d_in[3];
    float* out = (float*)d_out;
    (void)d_ws; (void)ws_size; (void)n_in; (void)in_sizes; (void)out_size;

    k1_absmax_cb<<<256, 256, 0, stream>>>(x, cbraw);
    k2_quant<<<205, 256, 0, stream>>>(x);
    k3_gemm<<<NBLK * KSPLIT, 256, 0, stream>>>(indices);
    k4_final<<<T_DIM * OUT_DIM / 4 / 256, 256, 0, stream>>>(scales, out);
}